// Round 10
// baseline (254.341 us; speedup 1.0000x reference)
//
#include <hip/hip_runtime.h>
#include <hip/hip_bf16.h>

#define TOKENS 512
#define IN_F 8192
#define OUT_F 8192
#define RANK 64
#define NNZ 8192

#define KSPLIT 4
#define KRANGE (IN_F / KSPLIT)   // 2048
#define BM 512
#define BN 64
#define NT 32                    // K-steps of 64 within KRANGE

typedef __attribute__((ext_vector_type(8))) short short8;
typedef __attribute__((ext_vector_type(4))) float f32x4;
typedef __attribute__((ext_vector_type(4))) int int4v;
typedef __attribute__((ext_vector_type(2))) int int2v;

__device__ __forceinline__ unsigned short f2bf(float f) {
  unsigned int u = __builtin_bit_cast(unsigned int, f);
  u += 0x7FFFu + ((u >> 16) & 1u);
  return (unsigned short)(u >> 16);
}
__device__ __forceinline__ float bf2f(unsigned short b) {
  unsigned int u = ((unsigned int)b) << 16;
  return __builtin_bit_cast(float, u);
}

__device__ __forceinline__ void gload_lds16(const void* g, void* l) {
  __builtin_amdgcn_global_load_lds(
      (const __attribute__((address_space(1))) unsigned int*)(g),
      (__attribute__((address_space(3))) unsigned int*)(l), 16, 0, 0);
}

#define WAIT_VM(n) asm volatile("s_waitcnt vmcnt(" #n ")" ::: "memory")
#define WAIT_LGKM0 asm volatile("s_waitcnt lgkmcnt(0)" ::: "memory")
#define SCHED0 __builtin_amdgcn_sched_barrier(0)

// K1: quantize x -> x_q; bf16 copy (lr1/outlier) and i8 copy (gemm)
__global__ __launch_bounds__(256) void k_quant(const float* __restrict__ x,
                                               const float* __restrict__ smooth,
                                               const float* __restrict__ act,
                                               unsigned short* __restrict__ Abf,
                                               unsigned char* __restrict__ Aq) {
  int idx = blockIdx.x * 256 + threadIdx.x;
  int base = idx * 4;
  int col = base & (IN_F - 1);
  float a = act[0];
  float4 xx = *(const float4*)(x + base);
  float4 ss = *(const float4*)(smooth + col);
  float q0 = fminf(fmaxf(rintf((xx.x / ss.x) / a), -128.f), 127.f);
  float q1 = fminf(fmaxf(rintf((xx.y / ss.y) / a), -128.f), 127.f);
  float q2 = fminf(fmaxf(rintf((xx.z / ss.z) / a), -128.f), 127.f);
  float q3 = fminf(fmaxf(rintf((xx.w / ss.w) / a), -128.f), 127.f);
  ushort4 o;
  o.x = f2bf(q0); o.y = f2bf(q1); o.z = f2bf(q2); o.w = f2bf(q3);
  *(ushort4*)(Abf + base) = o;
  int i0 = (int)q0, i1 = (int)q1, i2 = (int)q2, i3 = (int)q3;
  unsigned int p = (i0 & 0xFF) | ((i1 & 0xFF) << 8) | ((i2 & 0xFF) << 16) |
                   ((unsigned)(i3 & 0xFF) << 24);
  *(unsigned int*)(Aq + base) = p;
}

// K2: t[512][64] = (x_dq @ V) * S*a   (64 blocks, atomic K-split accum)
__global__ __launch_bounds__(256) void k_lr1(const unsigned short* __restrict__ Abf,
                                             const float* __restrict__ V,
                                             const float* __restrict__ S,
                                             const float* __restrict__ act,
                                             float* __restrict__ t) {
  int bid = blockIdx.x;
  int mb = (bid & 3) * 128;
  int kb0 = (bid >> 2) * 512;
  int tid = threadIdx.x, w = tid >> 6, l = tid & 63;
  int lr = l & 15, lg = l >> 4;
  f32x4 acc[2][4] = {};
  for (int ks = 0; ks < 16; ++ks) {
    int kb = kb0 + ks * 32;
    short8 af[2];
#pragma unroll
    for (int fi = 0; fi < 2; ++fi) {
      int row = mb + w * 32 + fi * 16 + lr;
      af[fi] = *(const short8*)(Abf + (size_t)row * IN_F + kb + lg * 8);
    }
    short8 bfr[4];
#pragma unroll
    for (int fj = 0; fj < 4; ++fj) {
      int rk = fj * 16 + lr;
      short8 bv;
#pragma unroll
      for (int j = 0; j < 8; ++j)
        bv[j] = (short)f2bf(V[(size_t)(kb + lg * 8 + j) * RANK + rk]);
      bfr[fj] = bv;
    }
#pragma unroll
    for (int fi = 0; fi < 2; ++fi)
#pragma unroll
      for (int fj = 0; fj < 4; ++fj)
        acc[fi][fj] = __builtin_amdgcn_mfma_f32_16x16x32_bf16(af[fi], bfr[fj], acc[fi][fj], 0, 0, 0);
  }
  float a = act[0];
#pragma unroll
  for (int fi = 0; fi < 2; ++fi)
#pragma unroll
    for (int fj = 0; fj < 4; ++fj) {
      int rk = fj * 16 + lr;
      float sc = a * S[rk];
#pragma unroll
      for (int r = 0; r < 4; ++r) {
        int tok = mb + w * 32 + fi * 16 + lg * 4 + r;
        atomicAdd(t + tok * RANK + rk, acc[fi][fj][r] * sc);
      }
    }
}

// K3: out = bias + t @ U^T   (first writer of out)
__global__ __launch_bounds__(256) void k_lr2(const float* __restrict__ t,
                                             const float* __restrict__ U,
                                             const float* __restrict__ bias,
                                             float* __restrict__ out) {
  int bid = blockIdx.x;
  int mb = (bid & 3) * 128;
  int nb = (bid >> 2) * 128;
  int tid = threadIdx.x, w = tid >> 6, l = tid & 63;
  int lr = l & 15, lg = l >> 4;
  int wm = w >> 1, wn = w & 1;
  f32x4 acc[4][4] = {};
#pragma unroll
  for (int kk = 0; kk < 2; ++kk) {
    short8 af[4], bfr[4];
#pragma unroll
    for (int fi = 0; fi < 4; ++fi) {
      int row = mb + wm * 64 + fi * 16 + lr;
      const float4* tp = (const float4*)(t + (size_t)row * RANK + kk * 32 + lg * 8);
      float4 t0 = tp[0], t1 = tp[1];
      af[fi][0] = f2bf(t0.x); af[fi][1] = f2bf(t0.y);
      af[fi][2] = f2bf(t0.z); af[fi][3] = f2bf(t0.w);
      af[fi][4] = f2bf(t1.x); af[fi][5] = f2bf(t1.y);
      af[fi][6] = f2bf(t1.z); af[fi][7] = f2bf(t1.w);
    }
#pragma unroll
    for (int fj = 0; fj < 4; ++fj) {
      int row = nb + wn * 64 + fj * 16 + lr;
      const float4* up = (const float4*)(U + (size_t)row * RANK + kk * 32 + lg * 8);
      float4 u0 = up[0], u1 = up[1];
      bfr[fj][0] = f2bf(u0.x); bfr[fj][1] = f2bf(u0.y);
      bfr[fj][2] = f2bf(u0.z); bfr[fj][3] = f2bf(u0.w);
      bfr[fj][4] = f2bf(u1.x); bfr[fj][5] = f2bf(u1.y);
      bfr[fj][6] = f2bf(u1.z); bfr[fj][7] = f2bf(u1.w);
    }
#pragma unroll
    for (int fi = 0; fi < 4; ++fi)
#pragma unroll
      for (int fj = 0; fj < 4; ++fj)
        acc[fi][fj] = __builtin_amdgcn_mfma_f32_16x16x32_bf16(af[fi], bfr[fj], acc[fi][fj], 0, 0, 0);
  }
#pragma unroll
  for (int fj = 0; fj < 4; ++fj) {
    int o = nb + wn * 64 + fj * 16 + lr;
    float b = bias[o];
#pragma unroll
    for (int fi = 0; fi < 4; ++fi)
#pragma unroll
      for (int r = 0; r < 4; ++r) {
        int tok = mb + wm * 64 + fi * 16 + lg * 4 + r;
        out[(size_t)tok * OUT_F + o] = b + acc[fi][fj][r];
      }
  }
}

// K4: outliers + merge of 4 int32 GEMM partial slices
__global__ __launch_bounds__(256) void k_outlier_merge(
    const unsigned short* __restrict__ Abf, const int* __restrict__ rows,
    const int* __restrict__ cols, const float* __restrict__ vals,
    const float* __restrict__ act, const float* __restrict__ wscale,
    const int* __restrict__ part, float* __restrict__ out) {
  __shared__ float accr[OUT_F];
  int tk = blockIdx.x;
  for (int i = threadIdx.x; i < OUT_F; i += 256) accr[i] = 0.f;
  __syncthreads();
  float a = act[0];
  for (int i = threadIdx.x; i < NNZ; i += 256) {
    int r = rows[i], c = cols[i];
    float v = vals[i];
    float xq = bf2f(Abf[(size_t)tk * IN_F + c]);
    atomicAdd(accr + r, a * xq * v);
  }
  __syncthreads();
  float* orow = out + (size_t)tk * OUT_F;
  const int* p0 = part + (size_t)tk * OUT_F;
  const int* p1 = p0 + (size_t)TOKENS * OUT_F;
  const int* p2 = p1 + (size_t)TOKENS * OUT_F;
  const int* p3 = p2 + (size_t)TOKENS * OUT_F;
  for (int i = threadIdx.x * 4; i < OUT_F; i += 1024) {
    int4v s0 = *(const int4v*)(p0 + i);
    int4v s1 = *(const int4v*)(p1 + i);
    int4v s2 = *(const int4v*)(p2 + i);
    int4v s3 = *(const int4v*)(p3 + i);
    float4 ws = *(const float4*)(wscale + i);
    float4 ov = *(const float4*)(orow + i);
    ov.x += accr[i + 0] + (float)(s0[0] + s1[0] + s2[0] + s3[0]) * a * ws.x;
    ov.y += accr[i + 1] + (float)(s0[1] + s1[1] + s2[1] + s3[1]) * a * ws.y;
    ov.z += accr[i + 2] + (float)(s0[2] + s1[2] + s2[2] + s3[2]) * a * ws.z;
    ov.w += accr[i + 3] + (float)(s0[3] + s1[3] + s2[3] + s3[3]) * a * ws.w;
    *(float4*)(orow + i) = ov;
  }
}

// K5: part[ks] = x_q @ Wq[:,slice]^T; i8 MFMA; 6-deep half-tile pipeline
// (T3+T4: 4 vmem ops in flight across 2 barriers, vmcnt never < 2 in-loop).
// BM=512, BN=64, KSPLIT=4; half = 32 k-cols; 1024 thr (16 waves), 1 blk/CU.
__global__ __launch_bounds__(1024, 4) void k_gemm(const unsigned char* __restrict__ Aq,
                                                  const int* __restrict__ W,
                                                  int* __restrict__ part) {
  __shared__ __align__(16) unsigned char As[6][512 * 32];  // 96 KB
  __shared__ __align__(16) unsigned char Bs[6][64 * 32];   // 12 KB

  // XCD pair {2k,2k+1} owns ks=k
  int d = blockIdx.x;
  int wg = (d & 7) * 64 + (d >> 3);   // 0..511
  int ks = wg >> 7;                   // 0..3
  int nb = wg & 127;                  // 0..127
  int kb0 = ks * KRANGE;

  int tid = threadIdx.x, w = tid >> 6, l = tid & 63;
  int lr = l & 15, lg = l >> 4;
  int wm = w >> 1, wn = w & 1;        // 8 wm x 2 wn; wave tile 64x32

  int4v acc[4][2] = {};
  int2v ws0, ws1;

  // A staging: unit = tid; r = tid>>1 (row 0..511), u = tid&1 (k-half-unit)
  const int rA = tid >> 1, uA = tid & 1;
  const int usA = uA ^ ((rA >> 2) & 1);
  // W staging: r = tid>>4 (row 0..63), kc = (tid&15)*2 int32s
  const int rW = tid >> 4, kcW = (tid & 15) * 2;
  const int usW = (kcW >> 4) ^ ((rW >> 2) & 1);
  const int offW = kcW & 15;

  auto STAGE_A = [&](int buf, int h) {
    gload_lds16(Aq + (size_t)rA * IN_F + kb0 + ((h * 32) & (KRANGE - 1)) + usA * 16,
                &As[buf][(size_t)(w * 64) * 16]);
  };
  auto LOAD_W = [&](int2v& wr, int h) {
    wr = *(const int2v*)(W + (size_t)(nb * BN + rW) * IN_F + kb0 +
                         ((h * 32) & (KRANGE - 1)) + kcW);
  };
  auto DSWRITE_B = [&](int buf, int2v wr) {
    unsigned short v = (unsigned short)((wr[0] & 0xFF) | ((wr[1] & 0xFF) << 8));
    *(unsigned short*)(&Bs[buf][rW * 32 + usW * 16 + offW]) = v;
  };
  // fragment read: k-quarter lg of the 64-k step; halves c0 (lg<2), c1 (lg>=2)
  auto LDFA = [&](int buf, int row) -> int4v {
    int us = (lg & 1) ^ ((row >> 2) & 1);
    return *(const int4v*)(&As[buf][(size_t)row * 32 + us * 16]);
  };
  auto LDFB = [&](int buf, int row) -> int4v {
    int us = (lg & 1) ^ ((row >> 2) & 1);
    return *(const int4v*)(&Bs[buf][(size_t)row * 32 + us * 16]);
  };

  // ---- prologue: fill halves 0..3, leave 4,5 in flight ----
  STAGE_A(0, 0); LOAD_W(ws0, 0);
  STAGE_A(1, 1); LOAD_W(ws1, 1);
  WAIT_VM(2); DSWRITE_B(0, ws0);
  WAIT_VM(0); DSWRITE_B(1, ws1);
  STAGE_A(2, 2); LOAD_W(ws0, 2);
  STAGE_A(3, 3); LOAD_W(ws1, 3);
  WAIT_VM(2); DSWRITE_B(2, ws0);
  WAIT_VM(0); DSWRITE_B(3, ws1);
  STAGE_A(4, 4); LOAD_W(ws0, 4);
  STAGE_A(5, 5); LOAD_W(ws1, 5);
  WAIT_LGKM0;
  SCHED0;
  __builtin_amdgcn_s_barrier();
  SCHED0;

  int c0 = 0;  // buffer of half 2t; c1 = c0+1 (pairs never wrap: 0,2,4)
  for (int t = 0; t < NT; ++t) {
    int c1 = c0 + 1;
    int w4 = c0 >= 2 ? c0 - 2 : c0 + 4;  // (c0+4)%6
    int w5 = w4 + 1;
    int bufsel = lg >> 1;
    int bA = bufsel ? c1 : c0;

    // phase A: fragment loads (halves 2t, 2t+1)
    int4v af0 = LDFA(bA, wm * 64 + 0 * 16 + lr);
    int4v af1 = LDFA(bA, wm * 64 + 1 * 16 + lr);
    int4v af2 = LDFA(bA, wm * 64 + 2 * 16 + lr);
    int4v af3 = LDFA(bA, wm * 64 + 3 * 16 + lr);
    int4v b0 = LDFB(bA, wn * 32 + lr);
    int4v b1 = LDFB(bA, wn * 32 + 16 + lr);
    WAIT_LGKM0;
    SCHED0;
    __builtin_amdgcn_s_barrier();   // #1 — bufs c0,c1 free for restage
    SCHED0;

    // phase C: retire half 2t+4, restage into c0
    WAIT_VM(2);
    DSWRITE_B(w4, ws0);
    STAGE_A(c0, 2 * t + 6);
    LOAD_W(ws0, 2 * t + 6);

    // phase D: MFMA (pure reg)
    __builtin_amdgcn_s_setprio(1);
    acc[0][0] = __builtin_amdgcn_mfma_i32_16x16x64_i8(af0, b0, acc[0][0], 0, 0, 0);
    acc[1][0] = __builtin_amdgcn_mfma_i32_16x16x64_i8(af1, b0, acc[1][0], 0, 0, 0);
    acc[2][0] = __builtin_amdgcn_mfma_i32_16x16x64_i8(af2, b0, acc[2][0], 0, 0, 0);
    acc[3][0] = __builtin_amdgcn_mfma_i32_16x16x64_i8(af3, b0, acc[3][0], 0, 0, 0);
    acc[0][1] = __builtin_amdgcn_mfma_i32_16x16x64_i8(af0, b1, acc[0][1], 0, 0, 0);
    acc[1][1] = __builtin_amdgcn_mfma_i32_16x16x64_i8(af1, b1, acc[1][1], 0, 0, 0);
    acc[2][1] = __builtin_amdgcn_mfma_i32_16x16x64_i8(af2, b1, acc[2][1], 0, 0, 0);
    acc[3][1] = __builtin_amdgcn_mfma_i32_16x16x64_i8(af3, b1, acc[3][1], 0, 0, 0);
    __builtin_amdgcn_s_setprio(0);

    // phase E: retire half 2t+5, restage into c1
    WAIT_VM(2);
    DSWRITE_B(w5, ws1);
    STAGE_A(c1, 2 * t + 7);
    LOAD_W(ws1, 2 * t + 7);
    WAIT_LGKM0;
    SCHED0;
    __builtin_amdgcn_s_barrier();   // #2
    SCHED0;

    c0 = c0 >= 4 ? 0 : c0 + 2;      // (c0+2)%6
  }

  // streaming i32 partial stores (unique writer per slice)
  int* pp = part + (size_t)ks * TOKENS * OUT_F;
#pragma unroll
  for (int fj = 0; fj < 2; ++fj) {
    int o = nb * BN + wn * 32 + fj * 16 + lr;
#pragma unroll
    for (int fi = 0; fi < 4; ++fi)
#pragma unroll
      for (int rr = 0; rr < 4; ++rr) {
        int tok = wm * 64 + fi * 16 + lg * 4 + rr;
        pp[(size_t)tok * OUT_F + o] = acc[fi][fj][rr];
      }
  }
}

extern "C" void kernel_launch(void* const* d_in, const int* in_sizes, int n_in,
                              void* d_out, int out_size, void* d_ws, size_t ws_size,
                              hipStream_t stream) {
  const float* x = (const float*)d_in[0];
  const int* W = (const int*)d_in[1];
  const float* wscale = (const float*)d_in[2];
  const float* smooth = (const float*)d_in[3];
  const float* act = (const float*)d_in[4];
  const int* orow = (const int*)d_in[5];
  const int* ocol = (const int*)d_in[6];
  const float* oval = (const float*)d_in[7];
  const float* U = (const float*)d_in[8];
  const float* S = (const float*)d_in[9];
  const float* V = (const float*)d_in[10];
  const float* bias = (const float*)d_in[11];
  float* out = (float*)d_out;

  unsigned short* Abf = (unsigned short*)d_ws;                           // 8 MB
  unsigned char* Aq = (unsigned char*)d_ws + (size_t)TOKENS * IN_F * 2;  // 4 MB
  float* t = (float*)((char*)d_ws + (size_t)TOKENS * IN_F * 3);          // 128 KB
  int* part = (int*)((char*)d_ws + (size_t)TOKENS * IN_F * 3 +
                     (size_t)TOKENS * RANK * 4);                         // 64 MB

  hipMemsetAsync(t, 0, TOKENS * RANK * sizeof(float), stream);
  k_quant<<<(TOKENS * IN_F / 4) / 256, 256, 0, stream>>>(x, smooth, act, Abf, Aq);
  k_gemm<<<512, 1024, 0, stream>>>(Aq, W, part);
  k_lr1<<<64, 256, 0, stream>>>(Abf, V, S, act, t);
  k_lr2<<<256, 256, 0, stream>>>(t, U, bias, out);
  k_outlier_merge<<<TOKENS, 256, 0, stream>>>(Abf, orow, ocol, oval, act,
                                              wscale, part, out);
}

// Round 11
// 186.356 us; speedup vs baseline: 1.3648x; 1.3648x over previous
//
#include <hip/hip_runtime.h>
#include <hip/hip_bf16.h>

#define TOKENS 512
#define IN_F 8192
#define OUT_F 8192
#define RANK 64
#define NNZ 8192

#define KSPLIT 4
#define KRANGE (IN_F / KSPLIT)   // 2048
#define BM 512
#define BN 128
#define BK 64
#define NT (KRANGE / BK)         // 32

typedef __attribute__((ext_vector_type(8))) short short8;
typedef __attribute__((ext_vector_type(4))) float f32x4;
typedef __attribute__((ext_vector_type(4))) int int4v;

__device__ __forceinline__ unsigned short f2bf(float f) {
  unsigned int u = __builtin_bit_cast(unsigned int, f);
  u += 0x7FFFu + ((u >> 16) & 1u);
  return (unsigned short)(u >> 16);
}
__device__ __forceinline__ float bf2f(unsigned short b) {
  unsigned int u = ((unsigned int)b) << 16;
  return __builtin_bit_cast(float, u);
}

__device__ __forceinline__ void gload_lds16(const void* g, void* l) {
  __builtin_amdgcn_global_load_lds(
      (const __attribute__((address_space(1))) unsigned int*)(g),
      (__attribute__((address_space(3))) unsigned int*)(l), 16, 0, 0);
}

#define WAIT_VM(n) asm volatile("s_waitcnt vmcnt(" #n ")" ::: "memory")
#define WAIT_LGKM0 asm volatile("s_waitcnt lgkmcnt(0)" ::: "memory")
#define SCHED0 __builtin_amdgcn_sched_barrier(0)

// K1: quantize x -> x_q; bf16 copy (lr1/outlier) and i8 copy (gemm)
__global__ __launch_bounds__(256) void k_quant(const float* __restrict__ x,
                                               const float* __restrict__ smooth,
                                               const float* __restrict__ act,
                                               unsigned short* __restrict__ Abf,
                                               unsigned char* __restrict__ Aq) {
  int idx = blockIdx.x * 256 + threadIdx.x;
  int base = idx * 4;
  int col = base & (IN_F - 1);
  float a = act[0];
  float4 xx = *(const float4*)(x + base);
  float4 ss = *(const float4*)(smooth + col);
  float q0 = fminf(fmaxf(rintf((xx.x / ss.x) / a), -128.f), 127.f);
  float q1 = fminf(fmaxf(rintf((xx.y / ss.y) / a), -128.f), 127.f);
  float q2 = fminf(fmaxf(rintf((xx.z / ss.z) / a), -128.f), 127.f);
  float q3 = fminf(fmaxf(rintf((xx.w / ss.w) / a), -128.f), 127.f);
  ushort4 o;
  o.x = f2bf(q0); o.y = f2bf(q1); o.z = f2bf(q2); o.w = f2bf(q3);
  *(ushort4*)(Abf + base) = o;
  int i0 = (int)q0, i1 = (int)q1, i2 = (int)q2, i3 = (int)q3;
  unsigned int p = (i0 & 0xFF) | ((i1 & 0xFF) << 8) | ((i2 & 0xFF) << 16) |
                   ((unsigned)(i3 & 0xFF) << 24);
  *(unsigned int*)(Aq + base) = p;
}

// K2: t[512][64] = (x_dq @ V) * S*a   (64 blocks, atomic K-split accum)
__global__ __launch_bounds__(256) void k_lr1(const unsigned short* __restrict__ Abf,
                                             const float* __restrict__ V,
                                             const float* __restrict__ S,
                                             const float* __restrict__ act,
                                             float* __restrict__ t) {
  int bid = blockIdx.x;
  int mb = (bid & 3) * 128;
  int kb0 = (bid >> 2) * 512;
  int tid = threadIdx.x, w = tid >> 6, l = tid & 63;
  int lr = l & 15, lg = l >> 4;
  f32x4 acc[2][4] = {};
  for (int ks = 0; ks < 16; ++ks) {
    int kb = kb0 + ks * 32;
    short8 af[2];
#pragma unroll
    for (int fi = 0; fi < 2; ++fi) {
      int row = mb + w * 32 + fi * 16 + lr;
      af[fi] = *(const short8*)(Abf + (size_t)row * IN_F + kb + lg * 8);
    }
    short8 bfr[4];
#pragma unroll
    for (int fj = 0; fj < 4; ++fj) {
      int rk = fj * 16 + lr;
      short8 bv;
#pragma unroll
      for (int j = 0; j < 8; ++j)
        bv[j] = (short)f2bf(V[(size_t)(kb + lg * 8 + j) * RANK + rk]);
      bfr[fj] = bv;
    }
#pragma unroll
    for (int fi = 0; fi < 2; ++fi)
#pragma unroll
      for (int fj = 0; fj < 4; ++fj)
        acc[fi][fj] = __builtin_amdgcn_mfma_f32_16x16x32_bf16(af[fi], bfr[fj], acc[fi][fj], 0, 0, 0);
  }
  float a = act[0];
#pragma unroll
  for (int fi = 0; fi < 2; ++fi)
#pragma unroll
    for (int fj = 0; fj < 4; ++fj) {
      int rk = fj * 16 + lr;
      float sc = a * S[rk];
#pragma unroll
      for (int r = 0; r < 4; ++r) {
        int tok = mb + w * 32 + fi * 16 + lg * 4 + r;
        atomicAdd(t + tok * RANK + rk, acc[fi][fj][r] * sc);
      }
    }
}

// K3: out = bias + t @ U^T   (first writer of out)
__global__ __launch_bounds__(256) void k_lr2(const float* __restrict__ t,
                                             const float* __restrict__ U,
                                             const float* __restrict__ bias,
                                             float* __restrict__ out) {
  int bid = blockIdx.x;
  int mb = (bid & 3) * 128;
  int nb = (bid >> 2) * 128;
  int tid = threadIdx.x, w = tid >> 6, l = tid & 63;
  int lr = l & 15, lg = l >> 4;
  int wm = w >> 1, wn = w & 1;
  f32x4 acc[4][4] = {};
#pragma unroll
  for (int kk = 0; kk < 2; ++kk) {
    short8 af[4], bfr[4];
#pragma unroll
    for (int fi = 0; fi < 4; ++fi) {
      int row = mb + wm * 64 + fi * 16 + lr;
      const float4* tp = (const float4*)(t + (size_t)row * RANK + kk * 32 + lg * 8);
      float4 t0 = tp[0], t1 = tp[1];
      af[fi][0] = f2bf(t0.x); af[fi][1] = f2bf(t0.y);
      af[fi][2] = f2bf(t0.z); af[fi][3] = f2bf(t0.w);
      af[fi][4] = f2bf(t1.x); af[fi][5] = f2bf(t1.y);
      af[fi][6] = f2bf(t1.z); af[fi][7] = f2bf(t1.w);
    }
#pragma unroll
    for (int fj = 0; fj < 4; ++fj) {
      int row = nb + wn * 64 + fj * 16 + lr;
      const float4* up = (const float4*)(U + (size_t)row * RANK + kk * 32 + lg * 8);
      float4 u0 = up[0], u1 = up[1];
      bfr[fj][0] = f2bf(u0.x); bfr[fj][1] = f2bf(u0.y);
      bfr[fj][2] = f2bf(u0.z); bfr[fj][3] = f2bf(u0.w);
      bfr[fj][4] = f2bf(u1.x); bfr[fj][5] = f2bf(u1.y);
      bfr[fj][6] = f2bf(u1.z); bfr[fj][7] = f2bf(u1.w);
    }
#pragma unroll
    for (int fi = 0; fi < 4; ++fi)
#pragma unroll
      for (int fj = 0; fj < 4; ++fj)
        acc[fi][fj] = __builtin_amdgcn_mfma_f32_16x16x32_bf16(af[fi], bfr[fj], acc[fi][fj], 0, 0, 0);
  }
#pragma unroll
  for (int fj = 0; fj < 4; ++fj) {
    int o = nb + wn * 64 + fj * 16 + lr;
    float b = bias[o];
#pragma unroll
    for (int fi = 0; fi < 4; ++fi)
#pragma unroll
      for (int r = 0; r < 4; ++r) {
        int tok = mb + wm * 64 + fi * 16 + lg * 4 + r;
        out[(size_t)tok * OUT_F + o] = b + acc[fi][fj][r];
      }
  }
}

// K4: outliers + merge of 4 int32 GEMM partial slices
__global__ __launch_bounds__(256) void k_outlier_merge(
    const unsigned short* __restrict__ Abf, const int* __restrict__ rows,
    const int* __restrict__ cols, const float* __restrict__ vals,
    const float* __restrict__ act, const float* __restrict__ wscale,
    const int* __restrict__ part, float* __restrict__ out) {
  __shared__ float accr[OUT_F];
  int tk = blockIdx.x;
  for (int i = threadIdx.x; i < OUT_F; i += 256) accr[i] = 0.f;
  __syncthreads();
  float a = act[0];
  for (int i = threadIdx.x; i < NNZ; i += 256) {
    int r = rows[i], c = cols[i];
    float v = vals[i];
    float xq = bf2f(Abf[(size_t)tk * IN_F + c]);
    atomicAdd(accr + r, a * xq * v);
  }
  __syncthreads();
  float* orow = out + (size_t)tk * OUT_F;
  const int* p0 = part + (size_t)tk * OUT_F;
  const int* p1 = p0 + (size_t)TOKENS * OUT_F;
  const int* p2 = p1 + (size_t)TOKENS * OUT_F;
  const int* p3 = p2 + (size_t)TOKENS * OUT_F;
  for (int i = threadIdx.x * 4; i < OUT_F; i += 1024) {
    int4v s0 = *(const int4v*)(p0 + i);
    int4v s1 = *(const int4v*)(p1 + i);
    int4v s2 = *(const int4v*)(p2 + i);
    int4v s3 = *(const int4v*)(p3 + i);
    float4 ws = *(const float4*)(wscale + i);
    float4 ov = *(const float4*)(orow + i);
    ov.x += accr[i + 0] + (float)(s0[0] + s1[0] + s2[0] + s3[0]) * a * ws.x;
    ov.y += accr[i + 1] + (float)(s0[1] + s1[1] + s2[1] + s3[1]) * a * ws.y;
    ov.z += accr[i + 2] + (float)(s0[2] + s1[2] + s2[2] + s3[2]) * a * ws.z;
    ov.w += accr[i + 3] + (float)(s0[3] + s1[3] + s2[3] + s3[3]) * a * ws.w;
    *(float4*)(orow + i) = ov;
  }
}

// K5: part[ks] = x_q @ Wq[:,slice]^T; i8 MFMA; BM=512, BN=128, KSPLIT=4.
// 3-deep LDS ring: A staged 2 iters ahead (gload_lds), W regs 1 iter ahead,
// WAIT_VM(4) keeps next tile's 4 vmem ops in flight across each barrier.
__global__ __launch_bounds__(1024, 4) void k_gemm(const unsigned char* __restrict__ Aq,
                                                  const int* __restrict__ W,
                                                  int* __restrict__ part) {
  __shared__ __align__(16) unsigned char As[3][BM * BK];  // 96 KB
  __shared__ __align__(16) unsigned char Bs[3][BN * BK];  // 24 KB

  // XCD pair {2k,2k+1} owns ks=k (A-slice 1MB L2-resident per XCD pair)
  int d = blockIdx.x;
  int wg = (d & 7) * 32 + (d >> 3);   // 0..255
  int ks = wg >> 6;                   // 0..3
  int nb = wg & 63;                   // 0..63
  int kb0 = ks * KRANGE;

  int tid = threadIdx.x, w = tid >> 6, l = tid & 63;
  int lr = l & 15, lg = l >> 4;
  int wm = w >> 1, wn = w & 1;        // 8 wm x 2 wn; wave tile 64x64

  int4v acc[4][4] = {};
  int4v wa[2], wb[2];

  const int rW = tid >> 3;            // W row 0..127
  const int kcW = (tid & 7) * 8;      // int32 (=i8 byte) offset within BK
  const int uW = (kcW >> 4) ^ ((rW >> 1) & 3);
  const int offW = kcW & 15;

  auto LOAD_W = [&](int4v (&wr)[2], int kt) {
    const int* wp = W + (size_t)(nb * BN + rW) * IN_F + kb0 +
                    (kt & (NT - 1)) * BK + kcW;
    wr[0] = *(const int4v*)wp;
    wr[1] = *(const int4v*)(wp + 4);
  };
  // A i8 -> LDS direct; linear dest, pre-swizzled source (u ^= (r>>1)&3)
  auto STAGE_A = [&](int buf, int kt) {
    int kb = kb0 + (kt & (NT - 1)) * BK;
#pragma unroll
    for (int i = 0; i < 2; ++i) {
      int lidx = i * 1024 + w * 64;
      int U = lidx + l;
      int r = U >> 2, up = U & 3;
      int u = up ^ ((r >> 1) & 3);
      gload_lds16(Aq + (size_t)r * IN_F + kb + u * 16, &As[buf][(size_t)lidx * 16]);
    }
  };
  auto DSWRITE_B = [&](int buf, const int4v (&wr)[2]) {
    unsigned int w0 = 0, w1 = 0;
#pragma unroll
    for (int j = 0; j < 4; ++j) w0 |= ((unsigned)(wr[0][j] & 0xFF)) << (8 * j);
#pragma unroll
    for (int j = 0; j < 4; ++j) w1 |= ((unsigned)(wr[1][j] & 0xFF)) << (8 * j);
    uint2 val; val.x = w0; val.y = w1;
    *(uint2*)(&Bs[buf][(size_t)rW * BK + uW * 16 + offW]) = val;
  };
  auto LDFA = [&](int buf, int row) -> int4v {
    int u = lg ^ ((row >> 1) & 3);
    return *(const int4v*)(&As[buf][(size_t)row * BK + u * 16]);
  };
  auto LDFB = [&](int buf, int row) -> int4v {
    int u = lg ^ ((row >> 1) & 3);
    return *(const int4v*)(&Bs[buf][(size_t)row * BK + u * 16]);
  };
  auto COMPUTE = [&](int buf) {
    int4v b0 = LDFB(buf, wn * 64 + 0 * 16 + lr);
    int4v b1 = LDFB(buf, wn * 64 + 1 * 16 + lr);
    int4v b2 = LDFB(buf, wn * 64 + 2 * 16 + lr);
    int4v b3 = LDFB(buf, wn * 64 + 3 * 16 + lr);
    __builtin_amdgcn_s_setprio(1);
#pragma unroll
    for (int fi = 0; fi < 4; ++fi) {
      int4v af = LDFA(buf, wm * 64 + fi * 16 + lr);
      acc[fi][0] = __builtin_amdgcn_mfma_i32_16x16x64_i8(af, b0, acc[fi][0], 0, 0, 0);
      acc[fi][1] = __builtin_amdgcn_mfma_i32_16x16x64_i8(af, b1, acc[fi][1], 0, 0, 0);
      acc[fi][2] = __builtin_amdgcn_mfma_i32_16x16x64_i8(af, b2, acc[fi][2], 0, 0, 0);
      acc[fi][3] = __builtin_amdgcn_mfma_i32_16x16x64_i8(af, b3, acc[fi][3], 0, 0, 0);
    }
    __builtin_amdgcn_s_setprio(0);
  };

  // prologue: A0,W0,A1,W1 issued; retire A0+W0, write B0; A1,W1 stay in flight
  STAGE_A(0, 0);
  LOAD_W(wa, 0);
  STAGE_A(1, 1);
  LOAD_W(wb, 1);
  WAIT_VM(4);
  DSWRITE_B(0, wa);
  WAIT_LGKM0;
  SCHED0;
  __builtin_amdgcn_s_barrier();
  SCHED0;

  // steady: iter kt stages A(kt+2), loads W(kt+2); WAIT_VM(4) retires tile
  // kt+1's loads; ds-writes B(kt+1); barrier. Tile kt+2 stays in flight.
  int c = 0;  // buf of tile kt
  for (int kt = 0; kt < NT; kt += 2) {
    int c1 = c + 1 == 3 ? 0 : c + 1;
    int c2 = c1 + 1 == 3 ? 0 : c1 + 1;
    // even iter
    STAGE_A(c2, kt + 2);
    LOAD_W(wa, kt + 2);
    COMPUTE(c);
    WAIT_VM(4);
    DSWRITE_B(c1, wb);
    WAIT_LGKM0;
    SCHED0;
    __builtin_amdgcn_s_barrier();
    SCHED0;
    // odd iter
    STAGE_A(c, kt + 3);
    LOAD_W(wb, kt + 3);
    COMPUTE(c1);
    WAIT_VM(4);
    DSWRITE_B(c2, wa);
    WAIT_LGKM0;
    SCHED0;
    __builtin_amdgcn_s_barrier();
    SCHED0;
    c = c2;
  }

  // streaming i32 partial stores (unique writer per slice)
  int* pp = part + (size_t)ks * TOKENS * OUT_F;
#pragma unroll
  for (int fj = 0; fj < 4; ++fj) {
    int o = nb * BN + wn * 64 + fj * 16 + lr;
#pragma unroll
    for (int fi = 0; fi < 4; ++fi)
#pragma unroll
      for (int rr = 0; rr < 4; ++rr) {
        int tok = wm * 64 + fi * 16 + lg * 4 + rr;
        pp[(size_t)tok * OUT_F + o] = acc[fi][fj][rr];
      }
  }
}

extern "C" void kernel_launch(void* const* d_in, const int* in_sizes, int n_in,
                              void* d_out, int out_size, void* d_ws, size_t ws_size,
                              hipStream_t stream) {
  const float* x = (const float*)d_in[0];
  const int* W = (const int*)d_in[1];
  const float* wscale = (const float*)d_in[2];
  const float* smooth = (const float*)d_in[3];
  const float* act = (const float*)d_in[4];
  const int* orow = (const int*)d_in[5];
  const int* ocol = (const int*)d_in[6];
  const float* oval = (const float*)d_in[7];
  const float* U = (const float*)d_in[8];
  const float* S = (const float*)d_in[9];
  const float* V = (const float*)d_in[10];
  const float* bias = (const float*)d_in[11];
  float* out = (float*)d_out;

  unsigned short* Abf = (unsigned short*)d_ws;                           // 8 MB
  unsigned char* Aq = (unsigned char*)d_ws + (size_t)TOKENS * IN_F * 2;  // 4 MB
  float* t = (float*)((char*)d_ws + (size_t)TOKENS * IN_F * 3);          // 128 KB
  int* part = (int*)((char*)d_ws + (size_t)TOKENS * IN_F * 3 +
                     (size_t)TOKENS * RANK * 4);                         // 64 MB

  hipMemsetAsync(t, 0, TOKENS * RANK * sizeof(float), stream);
  k_quant<<<(TOKENS * IN_F / 4) / 256, 256, 0, stream>>>(x, smooth, act, Abf, Aq);
  k_gemm<<<256, 1024, 0, stream>>>(Aq, W, part);
  k_lr1<<<64, 256, 0, stream>>>(Abf, V, S, act, t);
  k_lr2<<<256, 256, 0, stream>>>(t, U, bias, out);
  k_outlier_merge<<<TOKENS, 256, 0, stream>>>(Abf, orow, ocol, oval, act,
                                              wscale, part, out);
}